// Round 1
// baseline (168.597 us; speedup 1.0000x reference)
//
#include <hip/hip_runtime.h>

#define C_LENX 2048
#define Q_LENX 512
#define BATCH  32
#define HDIM   256
#define BH     (BATCH*HDIM)   // 8192
#define CBLK   64
#define QBLK   32
#define NWAVES 4
#define QH_PITCH 264          // 32 rows of 256 bf16, padded (528B, 16B-aligned, breaks pow2 banks)
#define QT_PITCH 40           // 256 rows of 32 bf16, padded (80B)
#define P_PITCH  40

typedef __attribute__((ext_vector_type(8))) short bf16x8;
typedef __attribute__((ext_vector_type(4))) float f32x4;

__device__ __forceinline__ unsigned short f2bf(float x) {
    unsigned int u = __float_as_uint(x);
    u += 0x7fffu + ((u >> 16) & 1u);        // round-to-nearest-even
    return (unsigned short)(u >> 16);
}
__device__ __forceinline__ float bf2f(unsigned short h) {
    return __uint_as_float(((unsigned int)h) << 16);
}

__global__ __launch_bounds__(256, 2)
void s2s_attn(const float* __restrict__ content,
              const float* __restrict__ question,
              const int*   __restrict__ qmask,
              float*       __restrict__ out)
{
    __shared__ unsigned short sQh[QBLK][QH_PITCH];   // question tile hi (row-major [q][h])
    __shared__ unsigned short sQl[QBLK][QH_PITCH];   // question tile lo
    __shared__ unsigned short sQt[HDIM][QT_PITCH];   // transposed hi ([h][q]) for PV B-operand
    __shared__ unsigned short sP [NWAVES][16][P_PITCH]; // per-wave P tile (16 c x 32 q)
    __shared__ int sMask[QBLK];

    const int tid  = threadIdx.x;
    const int wid  = tid >> 6;
    const int lane = tid & 63;
    const int lr   = lane & 15;   // fragment row / D col
    const int lg   = lane >> 4;   // k-group / D row group

    const int ct = blockIdx.x;
    const int b  = blockIdx.y;
    const int c0 = ct * CBLK;

    // ---- preload this wave's 16 content rows as hi/lo bf16 fragments (reused all q-tiles) ----
    bf16x8 chi[8], clo[8];
    {
        const float* cbase = content + (size_t)(c0 + wid*16 + lr) * BH + b*HDIM + lg*8;
        #pragma unroll
        for (int kc = 0; kc < 8; ++kc) {
            float4 x0 = *reinterpret_cast<const float4*>(cbase + kc*32);
            float4 x1 = *reinterpret_cast<const float4*>(cbase + kc*32 + 4);
            float xs[8] = {x0.x,x0.y,x0.z,x0.w,x1.x,x1.y,x1.z,x1.w};
            bf16x8 hi, lo;
            #pragma unroll
            for (int j = 0; j < 8; ++j) {
                unsigned short hb = f2bf(xs[j]);
                hi[j] = (short)hb;
                lo[j] = (short)f2bf(xs[j] - bf2f(hb));
            }
            chi[kc] = hi; clo[kc] = lo;
        }
    }

    f32x4 acc[16];
    #pragma unroll
    for (int n = 0; n < 16; ++n) { f32x4 z = {0.f,0.f,0.f,0.f}; acc[n] = z; }
    float m_run[4] = {-INFINITY,-INFINITY,-INFINITY,-INFINITY};
    float l_run[4] = {0.f,0.f,0.f,0.f};

    for (int qt = 0; qt < Q_LENX/QBLK; ++qt) {
        const int q0 = qt * QBLK;
        __syncthreads();   // everyone done reading previous tile
        // ---- stage Q tile (coalesced float4, split hi/lo) ----
        {
            const float* qbase = question + (size_t)q0 * BH + b*HDIM;
            #pragma unroll
            for (int i = 0; i < 8; ++i) {
                int f  = tid + i*256;          // 0..2047 float4 cells
                int qr = f >> 6;               // 0..31
                int h4 = (f & 63) << 2;        // 0..252
                float4 x = *reinterpret_cast<const float4*>(qbase + (size_t)qr * BH + h4);
                unsigned short h0=f2bf(x.x), h1=f2bf(x.y), h2=f2bf(x.z), h3=f2bf(x.w);
                ushort4 hv; hv.x=h0; hv.y=h1; hv.z=h2; hv.w=h3;
                ushort4 lv; lv.x=f2bf(x.x-bf2f(h0)); lv.y=f2bf(x.y-bf2f(h1));
                           lv.z=f2bf(x.z-bf2f(h2)); lv.w=f2bf(x.w-bf2f(h3));
                *reinterpret_cast<ushort4*>(&sQh[qr][h4]) = hv;
                *reinterpret_cast<ushort4*>(&sQl[qr][h4]) = lv;
            }
            if (tid < QBLK) sMask[tid] = qmask[b*Q_LENX + q0 + tid];
        }
        __syncthreads();
        // ---- build transposed hi tile sQt[h][q] (ushort4 along q) ----
        {
            #pragma unroll
            for (int i = 0; i < 8; ++i) {
                int f  = tid + i*256;          // 0..2047 = 256 h x 8 q4-blocks
                int h  = f >> 3;               // 0..255
                int q4 = (f & 7) << 2;         // 0..28
                ushort4 v;
                v.x = sQh[q4+0][h]; v.y = sQh[q4+1][h];
                v.z = sQh[q4+2][h]; v.w = sQh[q4+3][h];
                *reinterpret_cast<ushort4*>(&sQt[h][q4]) = v;
            }
        }
        __syncthreads();

        // ---- QK^T: S tile = 16 c-rows x 32 q, split hi/lo (3 chains) ----
        f32x4 sacc0 = {0.f,0.f,0.f,0.f};
        f32x4 sacc1 = {0.f,0.f,0.f,0.f};
        #pragma unroll
        for (int kc = 0; kc < 8; ++kc) {
            bf16x8 qh0 = *reinterpret_cast<bf16x8*>(&sQh[lr]   [kc*32 + lg*8]);
            bf16x8 ql0 = *reinterpret_cast<bf16x8*>(&sQl[lr]   [kc*32 + lg*8]);
            bf16x8 qh1 = *reinterpret_cast<bf16x8*>(&sQh[16+lr][kc*32 + lg*8]);
            bf16x8 ql1 = *reinterpret_cast<bf16x8*>(&sQl[16+lr][kc*32 + lg*8]);
            sacc0 = __builtin_amdgcn_mfma_f32_16x16x32_bf16(chi[kc], qh0, sacc0, 0, 0, 0);
            sacc0 = __builtin_amdgcn_mfma_f32_16x16x32_bf16(clo[kc], qh0, sacc0, 0, 0, 0);
            sacc0 = __builtin_amdgcn_mfma_f32_16x16x32_bf16(chi[kc], ql0, sacc0, 0, 0, 0);
            sacc1 = __builtin_amdgcn_mfma_f32_16x16x32_bf16(chi[kc], qh1, sacc1, 0, 0, 0);
            sacc1 = __builtin_amdgcn_mfma_f32_16x16x32_bf16(clo[kc], qh1, sacc1, 0, 0, 0);
            sacc1 = __builtin_amdgcn_mfma_f32_16x16x32_bf16(chi[kc], ql1, sacc1, 0, 0, 0);
        }

        // ---- online softmax (rows owned per (lg, reg); reduce across 16 lanes) ----
        const bool ok0 = sMask[lr]      != 0;
        const bool ok1 = sMask[16 + lr] != 0;
        float p0[4], p1[4], tmax[4];
        #pragma unroll
        for (int r = 0; r < 4; ++r) {
            float v0 = ok0 ? sacc0[r] : -INFINITY;
            float v1 = ok1 ? sacc1[r] : -INFINITY;
            p0[r] = v0; p1[r] = v1;
            tmax[r] = fmaxf(v0, v1);
        }
        #pragma unroll
        for (int off = 1; off < 16; off <<= 1) {
            #pragma unroll
            for (int r = 0; r < 4; ++r)
                tmax[r] = fmaxf(tmax[r], __shfl_xor(tmax[r], off, 64));
        }
        float scale[4];
        unsigned short pb0[4], pb1[4];
        float psum[4];
        #pragma unroll
        for (int r = 0; r < 4; ++r) {
            float mnew = fmaxf(m_run[r], tmax[r]);
            if (mnew == -INFINITY) {       // fully-masked so far: keep zeros
                scale[r] = 1.f;
                pb0[r] = 0; pb1[r] = 0;
                psum[r] = 0.f;
            } else {
                scale[r] = __expf(m_run[r] - mnew);   // m_run=-inf -> 0
                float e0 = __expf(p0[r] - mnew);      // p=-inf -> 0
                float e1 = __expf(p1[r] - mnew);
                pb0[r] = f2bf(e0); pb1[r] = f2bf(e1);
                // sum the ROUNDED weights so numerator/denominator cancel
                psum[r] = bf2f(pb0[r]) + bf2f(pb1[r]);
                m_run[r] = mnew;
            }
        }
        #pragma unroll
        for (int off = 1; off < 16; off <<= 1) {
            #pragma unroll
            for (int r = 0; r < 4; ++r)
                psum[r] += __shfl_xor(psum[r], off, 64);
        }
        #pragma unroll
        for (int r = 0; r < 4; ++r)
            l_run[r] = l_run[r] * scale[r] + psum[r];
        #pragma unroll
        for (int n = 0; n < 16; ++n) {
            #pragma unroll
            for (int r = 0; r < 4; ++r)
                acc[n][r] *= scale[r];
        }

        // ---- stash P (bf16) in per-wave LDS, repack as A-fragment ----
        #pragma unroll
        for (int r = 0; r < 4; ++r) {
            sP[wid][lg*4 + r][lr]      = pb0[r];
            sP[wid][lg*4 + r][16 + lr] = pb1[r];
        }
        bf16x8 pfrag = *reinterpret_cast<bf16x8*>(&sP[wid][lr][lg*8]);

        // ---- PV: out[16 c x 256 h] += P(16x32) * Q(32x256) ----
        #pragma unroll
        for (int n = 0; n < 16; ++n) {
            bf16x8 vfrag = *reinterpret_cast<bf16x8*>(&sQt[n*16 + lr][lg*8]);
            acc[n] = __builtin_amdgcn_mfma_f32_16x16x32_bf16(pfrag, vfrag, acc[n], 0, 0, 0);
        }
    }

    // ---- epilogue: normalize and store fp32 ----
    float rinv[4];
    #pragma unroll
    for (int r = 0; r < 4; ++r) rinv[r] = 1.f / l_run[r];
    float* obase = out + (size_t)(c0 + wid*16) * BH + b*HDIM;
    #pragma unroll
    for (int n = 0; n < 16; ++n) {
        #pragma unroll
        for (int r = 0; r < 4; ++r)
            obase[(size_t)(lg*4 + r) * BH + n*16 + lr] = acc[n][r] * rinv[r];
    }
}

extern "C" void kernel_launch(void* const* d_in, const int* in_sizes, int n_in,
                              void* d_out, int out_size, void* d_ws, size_t ws_size,
                              hipStream_t stream) {
    const float* content  = (const float*)d_in[0];
    const float* question = (const float*)d_in[1];
    const int*   mask     = (const int*)d_in[2];
    float*       out      = (float*)d_out;
    dim3 grid(C_LENX / CBLK, BATCH);
    s2s_attn<<<grid, 256, 0, stream>>>(content, question, mask, out);
}

// Round 3
// 132.915 us; speedup vs baseline: 1.2685x; 1.2685x over previous
//
#include <hip/hip_runtime.h>

#define C_LENX 2048
#define Q_LENX 512
#define BATCH  32
#define HDIM   256
#define BH     8192           // B*H
#define CBLK   64
#define QBLK   32
#define NQT    (Q_LENX/QBLK)  // 16
#define NWAVES 4
#define QH_PITCH 264          // 32 rows of 256 bf16, padded
#define QT_PITCH 40           // 256 rows of 32 bf16, padded
#define P_PITCH  40
#define TILE_ELEMS (QBLK*HDIM)   // 8192 shorts per blob tile

typedef __attribute__((ext_vector_type(8))) short bf16x8;
typedef __attribute__((ext_vector_type(4))) float f32x4;

__device__ __forceinline__ unsigned short f2bf(float x) {
    unsigned int u = __float_as_uint(x);
    u += 0x7fffu + ((u >> 16) & 1u);        // round-to-nearest-even
    return (unsigned short)(u >> 16);
}
__device__ __forceinline__ float bf2f(unsigned short h) {
    return __uint_as_float(((unsigned int)h) << 16);
}

// ---------------- prep: fp32 Q -> bf16 hi/lo blobs + transposed-hi blob ----------------
__global__ __launch_bounds__(256)
void q_prep(const float* __restrict__ question,
            unsigned short* __restrict__ qh,
            unsigned short* __restrict__ ql,
            unsigned short* __restrict__ qt)
{
    __shared__ unsigned short sHi[QBLK][QH_PITCH];
    const int tid = threadIdx.x;
    const int b  = blockIdx.x >> 4;
    const int t  = blockIdx.x & 15;
    const int q0 = t * QBLK;
    const float* qbase = question + (size_t)q0 * BH + b * HDIM;
    const size_t blob = (size_t)(b * NQT + t) * TILE_ELEMS;

    #pragma unroll
    for (int i = 0; i < 8; ++i) {
        int e  = tid + i * 256;          // float4 cell 0..2047
        int qr = e >> 6;                 // 0..31
        int h4 = (e & 63) << 2;          // 0..252
        float4 x = *reinterpret_cast<const float4*>(qbase + (size_t)qr * BH + h4);
        ushort4 hv, lv;
        hv.x = f2bf(x.x); hv.y = f2bf(x.y); hv.z = f2bf(x.z); hv.w = f2bf(x.w);
        lv.x = f2bf(x.x - bf2f(hv.x)); lv.y = f2bf(x.y - bf2f(hv.y));
        lv.z = f2bf(x.z - bf2f(hv.z)); lv.w = f2bf(x.w - bf2f(hv.w));
        *reinterpret_cast<ushort4*>(&sHi[qr][h4]) = hv;
        *reinterpret_cast<ushort4*>(qh + blob + (size_t)qr * HDIM + h4) = hv;
        *reinterpret_cast<ushort4*>(ql + blob + (size_t)qr * HDIM + h4) = lv;
    }
    __syncthreads();
    #pragma unroll
    for (int i = 0; i < 8; ++i) {
        int e  = tid + i * 256;          // ushort4 cell of Qt, 0..2047
        int h  = e >> 3;                 // 0..255
        int q4 = (e & 7) << 2;           // 0..28
        ushort4 v;
        v.x = sHi[q4 + 0][h]; v.y = sHi[q4 + 1][h];
        v.z = sHi[q4 + 2][h]; v.w = sHi[q4 + 3][h];
        *reinterpret_cast<ushort4*>(qt + blob + (size_t)h * QBLK + q4) = v;
    }
}

// ---------------- main fused attention ----------------
__global__ __launch_bounds__(256, 2)
void s2s_attn(const float* __restrict__ content,
              const unsigned short* __restrict__ qh_blob,
              const unsigned short* __restrict__ ql_blob,
              const unsigned short* __restrict__ qt_blob,
              const int*   __restrict__ qmask,
              float*       __restrict__ out)
{
    __shared__ unsigned short sQh[QBLK][QH_PITCH];
    __shared__ unsigned short sQl[QBLK][QH_PITCH];
    __shared__ unsigned short sQt[HDIM][QT_PITCH];
    __shared__ unsigned short sP [NWAVES][16][P_PITCH];
    __shared__ int sMaskAll[Q_LENX];

    const int tid  = threadIdx.x;
    const int wid  = tid >> 6;
    const int lane = tid & 63;
    const int lr   = lane & 15;
    const int lg   = lane >> 4;

    const int ct = blockIdx.x;
    const int b  = blockIdx.y;
    const int c0 = ct * CBLK;

    for (int i = tid; i < Q_LENX; i += 256) sMaskAll[i] = qmask[b * Q_LENX + i];

    // ---- preload this wave's 16 content rows as hi/lo bf16 fragments ----
    bf16x8 chi[8], clo[8];
    {
        const float* cbase = content + (size_t)(c0 + wid*16 + lr) * BH + b*HDIM + lg*8;
        #pragma unroll
        for (int kc = 0; kc < 8; ++kc) {
            float4 x0 = *reinterpret_cast<const float4*>(cbase + kc*32);
            float4 x1 = *reinterpret_cast<const float4*>(cbase + kc*32 + 4);
            float xs[8] = {x0.x,x0.y,x0.z,x0.w,x1.x,x1.y,x1.z,x1.w};
            bf16x8 hi, lo;
            #pragma unroll
            for (int j = 0; j < 8; ++j) {
                unsigned short hb = f2bf(xs[j]);
                hi[j] = (short)hb;
                lo[j] = (short)f2bf(xs[j] - bf2f(hb));
            }
            chi[kc] = hi; clo[kc] = lo;
        }
    }

    f32x4 acc[16];
    #pragma unroll
    for (int n = 0; n < 16; ++n) { f32x4 z = {0.f,0.f,0.f,0.f}; acc[n] = z; }
    float m_run[4] = {-INFINITY,-INFINITY,-INFINITY,-INFINITY};
    float l_run[4] = {0.f,0.f,0.f,0.f};

    for (int qt = 0; qt < NQT; ++qt) {
        const int q0 = qt * QBLK;
        const size_t blob = (size_t)(b * NQT + qt) * TILE_ELEMS;
        __syncthreads();   // previous tile fully consumed
        // ---- stage bf16 tiles (pure vector copies): 1024 bf16x8 cells per blob ----
        #pragma unroll
        for (int i = 0; i < 4; ++i) {
            int e  = tid + i * 256;          // bf16x8 cell 0..1023
            int qr = e >> 5;                 // 0..31
            int h8 = (e & 31) << 3;          // 0..248
            *reinterpret_cast<bf16x8*>(&sQh[qr][h8]) =
                *reinterpret_cast<const bf16x8*>(qh_blob + blob + e*8);
            *reinterpret_cast<bf16x8*>(&sQl[qr][h8]) =
                *reinterpret_cast<const bf16x8*>(ql_blob + blob + e*8);
            int h  = e >> 2;                 // 0..255
            int q8 = (e & 3) << 3;           // 0..24
            *reinterpret_cast<bf16x8*>(&sQt[h][q8]) =
                *reinterpret_cast<const bf16x8*>(qt_blob + blob + e*8);
        }
        __syncthreads();

        // ---- QK^T: 16 c-rows x 32 q, hi/lo split (3 chains) ----
        f32x4 sacc0 = {0.f,0.f,0.f,0.f};
        f32x4 sacc1 = {0.f,0.f,0.f,0.f};
        #pragma unroll
        for (int kc = 0; kc < 8; ++kc) {
            bf16x8 qh0 = *reinterpret_cast<bf16x8*>(&sQh[lr]   [kc*32 + lg*8]);
            bf16x8 ql0 = *reinterpret_cast<bf16x8*>(&sQl[lr]   [kc*32 + lg*8]);
            bf16x8 qh1 = *reinterpret_cast<bf16x8*>(&sQh[16+lr][kc*32 + lg*8]);
            bf16x8 ql1 = *reinterpret_cast<bf16x8*>(&sQl[16+lr][kc*32 + lg*8]);
            sacc0 = __builtin_amdgcn_mfma_f32_16x16x32_bf16(chi[kc], qh0, sacc0, 0, 0, 0);
            sacc0 = __builtin_amdgcn_mfma_f32_16x16x32_bf16(clo[kc], qh0, sacc0, 0, 0, 0);
            sacc0 = __builtin_amdgcn_mfma_f32_16x16x32_bf16(chi[kc], ql0, sacc0, 0, 0, 0);
            sacc1 = __builtin_amdgcn_mfma_f32_16x16x32_bf16(chi[kc], qh1, sacc1, 0, 0, 0);
            sacc1 = __builtin_amdgcn_mfma_f32_16x16x32_bf16(clo[kc], qh1, sacc1, 0, 0, 0);
            sacc1 = __builtin_amdgcn_mfma_f32_16x16x32_bf16(chi[kc], ql1, sacc1, 0, 0, 0);
        }

        // ---- online softmax with defer-max (T13, THR=4) ----
        const bool ok0 = sMaskAll[q0 + lr]      != 0;
        const bool ok1 = sMaskAll[q0 + 16 + lr] != 0;
        float p0[4], p1[4], tmax[4];
        #pragma unroll
        for (int r = 0; r < 4; ++r) {
            float v0 = ok0 ? sacc0[r] : -INFINITY;
            float v1 = ok1 ? sacc1[r] : -INFINITY;
            p0[r] = v0; p1[r] = v1;
            tmax[r] = fmaxf(v0, v1);
        }
        #pragma unroll
        for (int off = 1; off < 16; off <<= 1) {
            #pragma unroll
            for (int r = 0; r < 4; ++r)
                tmax[r] = fmaxf(tmax[r], __shfl_xor(tmax[r], off, 64));
        }
        bool need = false;
        #pragma unroll
        for (int r = 0; r < 4; ++r) need |= (tmax[r] > m_run[r] + 4.0f);
        if (__ballot(need)) {           // wave-uniform rescale
            float scale[4];
            #pragma unroll
            for (int r = 0; r < 4; ++r) {
                float mnew = fmaxf(m_run[r], tmax[r]);
                if (mnew == -INFINITY) { scale[r] = 1.f; }
                else { scale[r] = __expf(m_run[r] - mnew); m_run[r] = mnew; }
                l_run[r] *= scale[r];
            }
            #pragma unroll
            for (int n = 0; n < 16; ++n) {
                #pragma unroll
                for (int r = 0; r < 4; ++r)
                    acc[n][r] *= scale[r];
            }
        }
        unsigned short pb0[4], pb1[4];
        float psum[4];
        #pragma unroll
        for (int r = 0; r < 4; ++r) {
            if (m_run[r] == -INFINITY) {
                pb0[r] = 0; pb1[r] = 0; psum[r] = 0.f;
            } else {
                float e0 = __expf(p0[r] - m_run[r]);   // bounded by e^4
                float e1 = __expf(p1[r] - m_run[r]);
                pb0[r] = f2bf(e0); pb1[r] = f2bf(e1);
                psum[r] = bf2f(pb0[r]) + bf2f(pb1[r]); // sum ROUNDED weights
            }
        }
        #pragma unroll
        for (int off = 1; off < 16; off <<= 1) {
            #pragma unroll
            for (int r = 0; r < 4; ++r)
                psum[r] += __shfl_xor(psum[r], off, 64);
        }
        #pragma unroll
        for (int r = 0; r < 4; ++r)
            l_run[r] += psum[r];

        // ---- stash P (bf16) in per-wave LDS, repack as A-fragment ----
        #pragma unroll
        for (int r = 0; r < 4; ++r) {
            sP[wid][lg*4 + r][lr]      = pb0[r];
            sP[wid][lg*4 + r][16 + lr] = pb1[r];
        }
        bf16x8 pfrag = *reinterpret_cast<bf16x8*>(&sP[wid][lr][lg*8]);

        // ---- PV: out[16 c x 256 h] += P(16x32) * Q(32x256) ----
        #pragma unroll
        for (int n = 0; n < 16; ++n) {
            bf16x8 vfrag = *reinterpret_cast<bf16x8*>(&sQt[n*16 + lr][lg*8]);
            acc[n] = __builtin_amdgcn_mfma_f32_16x16x32_bf16(pfrag, vfrag, acc[n], 0, 0, 0);
        }
    }

    // ---- epilogue ----
    float rinv[4];
    #pragma unroll
    for (int r = 0; r < 4; ++r) rinv[r] = 1.f / l_run[r];
    float* obase = out + (size_t)(c0 + wid*16) * BH + b*HDIM;
    #pragma unroll
    for (int n = 0; n < 16; ++n) {
        #pragma unroll
        for (int r = 0; r < 4; ++r)
            obase[(size_t)(lg*4 + r) * BH + n*16 + lr] = acc[n][r] * rinv[r];
    }
}

extern "C" void kernel_launch(void* const* d_in, const int* in_sizes, int n_in,
                              void* d_out, int out_size, void* d_ws, size_t ws_size,
                              hipStream_t stream) {
    const float* content  = (const float*)d_in[0];
    const float* question = (const float*)d_in[1];
    const int*   mask     = (const int*)d_in[2];
    float*       out      = (float*)d_out;

    unsigned short* qh = (unsigned short*)d_ws;                       // 8 MB
    unsigned short* ql = qh + (size_t)BATCH * NQT * TILE_ELEMS;       // 8 MB
    unsigned short* qt = ql + (size_t)BATCH * NQT * TILE_ELEMS;       // 8 MB

    q_prep<<<BATCH * NQT, 256, 0, stream>>>(question, qh, ql, qt);
    dim3 grid(C_LENX / CBLK, BATCH);
    s2s_attn<<<grid, 256, 0, stream>>>(content, qh, ql, qt, mask, out);
}

// Round 4
// 126.244 us; speedup vs baseline: 1.3355x; 1.0528x over previous
//
#include <hip/hip_runtime.h>

#define C_LENX 2048
#define Q_LENX 512
#define BATCH  32
#define HDIM   256
#define BH     8192           // B*H
#define CBLK   64
#define QBLK   32
#define NQT    (Q_LENX/QBLK)  // 16
#define NWAVES 4
#define QH_PITCH 264          // 32 rows of 256 bf16, padded
#define QT_PITCH 40           // 256 rows of 32 bf16, padded
#define P_PITCH  40
#define TILE_ELEMS (QBLK*HDIM)   // 8192 shorts per blob tile

typedef __attribute__((ext_vector_type(8))) short bf16x8;
typedef __attribute__((ext_vector_type(4))) float f32x4;

__device__ __forceinline__ unsigned short f2bf(float x) {
    unsigned int u = __float_as_uint(x);
    u += 0x7fffu + ((u >> 16) & 1u);        // round-to-nearest-even
    return (unsigned short)(u >> 16);
}
__device__ __forceinline__ float bf2f(unsigned short h) {
    return __uint_as_float(((unsigned int)h) << 16);
}

// ---------------- prep: fp32 Q -> bf16 hi/lo blobs + transposed-hi blob ----------------
__global__ __launch_bounds__(256)
void q_prep(const float* __restrict__ question,
            unsigned short* __restrict__ qh,
            unsigned short* __restrict__ ql,
            unsigned short* __restrict__ qt)
{
    __shared__ unsigned short sHi[QBLK][QH_PITCH];
    const int tid = threadIdx.x;
    const int b  = blockIdx.x >> 4;
    const int t  = blockIdx.x & 15;
    const int q0 = t * QBLK;
    const float* qbase = question + (size_t)q0 * BH + b * HDIM;
    const size_t blob = (size_t)(b * NQT + t) * TILE_ELEMS;

    #pragma unroll
    for (int i = 0; i < 8; ++i) {
        int e  = tid + i * 256;          // float4 cell 0..2047
        int qr = e >> 6;                 // 0..31
        int h4 = (e & 63) << 2;          // 0..252
        float4 x = *reinterpret_cast<const float4*>(qbase + (size_t)qr * BH + h4);
        ushort4 hv, lv;
        hv.x = f2bf(x.x); hv.y = f2bf(x.y); hv.z = f2bf(x.z); hv.w = f2bf(x.w);
        lv.x = f2bf(x.x - bf2f(hv.x)); lv.y = f2bf(x.y - bf2f(hv.y));
        lv.z = f2bf(x.z - bf2f(hv.z)); lv.w = f2bf(x.w - bf2f(hv.w));
        *reinterpret_cast<ushort4*>(&sHi[qr][h4]) = hv;
        *reinterpret_cast<ushort4*>(qh + blob + (size_t)qr * HDIM + h4) = hv;
        *reinterpret_cast<ushort4*>(ql + blob + (size_t)qr * HDIM + h4) = lv;
    }
    __syncthreads();
    #pragma unroll
    for (int i = 0; i < 8; ++i) {
        int e  = tid + i * 256;          // ushort4 cell of Qt, 0..2047
        int h  = e >> 3;                 // 0..255
        int q4 = (e & 7) << 2;           // 0..28
        ushort4 v;
        v.x = sHi[q4 + 0][h]; v.y = sHi[q4 + 1][h];
        v.z = sHi[q4 + 2][h]; v.w = sHi[q4 + 3][h];
        *reinterpret_cast<ushort4*>(qt + blob + (size_t)h * QBLK + q4) = v;
    }
}

// ---------------- main fused attention ----------------
__global__ __launch_bounds__(256, 2)
void s2s_attn(const float* __restrict__ content,
              const unsigned short* __restrict__ qh_blob,
              const unsigned short* __restrict__ ql_blob,
              const unsigned short* __restrict__ qt_blob,
              const int*   __restrict__ qmask,
              float*       __restrict__ out)
{
    __shared__ unsigned short sQh[QBLK][QH_PITCH];
    __shared__ unsigned short sQl[QBLK][QH_PITCH];
    __shared__ unsigned short sQt[HDIM][QT_PITCH];
    __shared__ unsigned short sP [NWAVES][16][P_PITCH];
    __shared__ int sMaskAll[Q_LENX];

    const int tid  = threadIdx.x;
    const int wid  = tid >> 6;
    const int lane = tid & 63;
    const int lr   = lane & 15;
    const int lg   = lane >> 4;

    // XCD-aware swizzle: each XCD owns 4 complete batches (blob L2 locality)
    const int lin = (blockIdx.x & 7) * 128 + (blockIdx.x >> 3);
    const int ct = lin & 31;        // 0..31 c-tile
    const int b  = lin >> 5;        // 0..31 batch
    const int c0 = ct * CBLK;

    for (int i = tid; i < Q_LENX; i += 256) sMaskAll[i] = qmask[b * Q_LENX + i];

    // ---- prologue: issue tile-0 staging loads (latency hides under C preload) ----
    bf16x8 stg[12];
    {
        const size_t blob0 = (size_t)(b * NQT + 0) * TILE_ELEMS;
        #pragma unroll
        for (int i = 0; i < 4; ++i) {
            int e = tid + i * 256;
            stg[i]     = *reinterpret_cast<const bf16x8*>(qh_blob + blob0 + (size_t)e * 8);
            stg[4 + i] = *reinterpret_cast<const bf16x8*>(ql_blob + blob0 + (size_t)e * 8);
            stg[8 + i] = *reinterpret_cast<const bf16x8*>(qt_blob + blob0 + (size_t)e * 8);
        }
    }

    // ---- preload this wave's 16 content rows as hi/lo bf16 fragments ----
    bf16x8 chi[8], clo[8];
    {
        const float* cbase = content + (size_t)(c0 + wid*16 + lr) * BH + b*HDIM + lg*8;
        #pragma unroll
        for (int kc = 0; kc < 8; ++kc) {
            float4 x0 = *reinterpret_cast<const float4*>(cbase + kc*32);
            float4 x1 = *reinterpret_cast<const float4*>(cbase + kc*32 + 4);
            float xs[8] = {x0.x,x0.y,x0.z,x0.w,x1.x,x1.y,x1.z,x1.w};
            bf16x8 hi, lo;
            #pragma unroll
            for (int j = 0; j < 8; ++j) {
                unsigned short hb = f2bf(xs[j]);
                hi[j] = (short)hb;
                lo[j] = (short)f2bf(xs[j] - bf2f(hb));
            }
            chi[kc] = hi; clo[kc] = lo;
        }
    }

    f32x4 acc[16];
    #pragma unroll
    for (int n = 0; n < 16; ++n) { f32x4 z = {0.f,0.f,0.f,0.f}; acc[n] = z; }
    float m_run[4] = {-INFINITY,-INFINITY,-INFINITY,-INFINITY};
    float l_run[4] = {0.f,0.f,0.f,0.f};

    for (int qt = 0; qt < NQT; ++qt) {
        const int q0 = qt * QBLK;
        __syncthreads();   // previous tile fully consumed; stg regs hold tile qt
        // ---- ds_write staged tile ----
        #pragma unroll
        for (int i = 0; i < 4; ++i) {
            int e  = tid + i * 256;          // bf16x8 cell 0..1023
            int qr = e >> 5;                 // 0..31
            int h8 = (e & 31) << 3;          // 0..248
            *reinterpret_cast<bf16x8*>(&sQh[qr][h8]) = stg[i];
            *reinterpret_cast<bf16x8*>(&sQl[qr][h8]) = stg[4 + i];
            int h  = e >> 2;                 // 0..255
            int q8 = (e & 3) << 3;           // 0..24
            *reinterpret_cast<bf16x8*>(&sQt[h][q8]) = stg[8 + i];
        }
        __syncthreads();
        // ---- T14: issue NEXT tile's global loads now; latency hides under compute ----
        if (qt + 1 < NQT) {
            const size_t blobn = (size_t)(b * NQT + qt + 1) * TILE_ELEMS;
            #pragma unroll
            for (int i = 0; i < 4; ++i) {
                int e = tid + i * 256;
                stg[i]     = *reinterpret_cast<const bf16x8*>(qh_blob + blobn + (size_t)e * 8);
                stg[4 + i] = *reinterpret_cast<const bf16x8*>(ql_blob + blobn + (size_t)e * 8);
                stg[8 + i] = *reinterpret_cast<const bf16x8*>(qt_blob + blobn + (size_t)e * 8);
            }
        }

        // ---- QK^T: 16 c-rows x 32 q, hi/lo split (3 chains) ----
        f32x4 sacc0 = {0.f,0.f,0.f,0.f};
        f32x4 sacc1 = {0.f,0.f,0.f,0.f};
        #pragma unroll
        for (int kc = 0; kc < 8; ++kc) {
            bf16x8 qh0 = *reinterpret_cast<bf16x8*>(&sQh[lr]   [kc*32 + lg*8]);
            bf16x8 ql0 = *reinterpret_cast<bf16x8*>(&sQl[lr]   [kc*32 + lg*8]);
            bf16x8 qh1 = *reinterpret_cast<bf16x8*>(&sQh[16+lr][kc*32 + lg*8]);
            bf16x8 ql1 = *reinterpret_cast<bf16x8*>(&sQl[16+lr][kc*32 + lg*8]);
            sacc0 = __builtin_amdgcn_mfma_f32_16x16x32_bf16(chi[kc], qh0, sacc0, 0, 0, 0);
            sacc0 = __builtin_amdgcn_mfma_f32_16x16x32_bf16(clo[kc], qh0, sacc0, 0, 0, 0);
            sacc0 = __builtin_amdgcn_mfma_f32_16x16x32_bf16(chi[kc], ql0, sacc0, 0, 0, 0);
            sacc1 = __builtin_amdgcn_mfma_f32_16x16x32_bf16(chi[kc], qh1, sacc1, 0, 0, 0);
            sacc1 = __builtin_amdgcn_mfma_f32_16x16x32_bf16(clo[kc], qh1, sacc1, 0, 0, 0);
            sacc1 = __builtin_amdgcn_mfma_f32_16x16x32_bf16(chi[kc], ql1, sacc1, 0, 0, 0);
        }

        // ---- online softmax with defer-max (T13, THR=4) ----
        const bool ok0 = sMaskAll[q0 + lr]      != 0;
        const bool ok1 = sMaskAll[q0 + 16 + lr] != 0;
        float p0[4], p1[4], tmax[4];
        #pragma unroll
        for (int r = 0; r < 4; ++r) {
            float v0 = ok0 ? sacc0[r] : -INFINITY;
            float v1 = ok1 ? sacc1[r] : -INFINITY;
            p0[r] = v0; p1[r] = v1;
            tmax[r] = fmaxf(v0, v1);
        }
        #pragma unroll
        for (int off = 1; off < 16; off <<= 1) {
            #pragma unroll
            for (int r = 0; r < 4; ++r)
                tmax[r] = fmaxf(tmax[r], __shfl_xor(tmax[r], off, 64));
        }
        bool need = false;
        #pragma unroll
        for (int r = 0; r < 4; ++r) need |= (tmax[r] > m_run[r] + 4.0f);
        if (__ballot(need)) {           // wave-uniform rescale
            float scale[4];
            #pragma unroll
            for (int r = 0; r < 4; ++r) {
                float mnew = fmaxf(m_run[r], tmax[r]);
                if (mnew == -INFINITY) { scale[r] = 1.f; }
                else { scale[r] = __expf(m_run[r] - mnew); m_run[r] = mnew; }
                l_run[r] *= scale[r];
            }
            #pragma unroll
            for (int n = 0; n < 16; ++n) {
                #pragma unroll
                for (int r = 0; r < 4; ++r)
                    acc[n][r] *= scale[r];
            }
        }
        unsigned short pb0[4], pb1[4];
        float psum[4];
        #pragma unroll
        for (int r = 0; r < 4; ++r) {
            if (m_run[r] == -INFINITY) {
                pb0[r] = 0; pb1[r] = 0; psum[r] = 0.f;
            } else {
                float e0 = __expf(p0[r] - m_run[r]);   // bounded by e^4
                float e1 = __expf(p1[r] - m_run[r]);
                pb0[r] = f2bf(e0); pb1[r] = f2bf(e1);
                psum[r] = bf2f(pb0[r]) + bf2f(pb1[r]); // sum ROUNDED weights
            }
        }
        #pragma unroll
        for (int off = 1; off < 16; off <<= 1) {
            #pragma unroll
            for (int r = 0; r < 4; ++r)
                psum[r] += __shfl_xor(psum[r], off, 64);
        }
        #pragma unroll
        for (int r = 0; r < 4; ++r)
            l_run[r] += psum[r];

        // ---- stash P (bf16) in per-wave LDS, repack as A-fragment ----
        #pragma unroll
        for (int r = 0; r < 4; ++r) {
            sP[wid][lg*4 + r][lr]      = pb0[r];
            sP[wid][lg*4 + r][16 + lr] = pb1[r];
        }
        bf16x8 pfrag = *reinterpret_cast<bf16x8*>(&sP[wid][lr][lg*8]);

        // ---- PV: out[16 c x 256 h] += P(16x32) * Q(32x256) ----
        #pragma unroll
        for (int n = 0; n < 16; ++n) {
            bf16x8 vfrag = *reinterpret_cast<bf16x8*>(&sQt[n*16 + lr][lg*8]);
            acc[n] = __builtin_amdgcn_mfma_f32_16x16x32_bf16(pfrag, vfrag, acc[n], 0, 0, 0);
        }
    }

    // ---- epilogue ----
    float rinv[4];
    #pragma unroll
    for (int r = 0; r < 4; ++r) rinv[r] = 1.f / l_run[r];
    float* obase = out + (size_t)(c0 + wid*16) * BH + b*HDIM;
    #pragma unroll
    for (int n = 0; n < 16; ++n) {
        #pragma unroll
        for (int r = 0; r < 4; ++r)
            obase[(size_t)(lg*4 + r) * BH + n*16 + lr] = acc[n][r] * rinv[r];
    }
}

extern "C" void kernel_launch(void* const* d_in, const int* in_sizes, int n_in,
                              void* d_out, int out_size, void* d_ws, size_t ws_size,
                              hipStream_t stream) {
    const float* content  = (const float*)d_in[0];
    const float* question = (const float*)d_in[1];
    const int*   mask     = (const int*)d_in[2];
    float*       out      = (float*)d_out;

    unsigned short* qh = (unsigned short*)d_ws;                       // 8 MB
    unsigned short* ql = qh + (size_t)BATCH * NQT * TILE_ELEMS;       // 8 MB
    unsigned short* qt = ql + (size_t)BATCH * NQT * TILE_ELEMS;       // 8 MB

    q_prep<<<BATCH * NQT, 256, 0, stream>>>(question, qh, ql, qt);
    s2s_attn<<<C_LENX / CBLK * BATCH, 256, 0, stream>>>(content, qh, ql, qt, mask, out);
}